// Round 1
// baseline (650.540 us; speedup 1.0000x reference)
//
#include <hip/hip_runtime.h>
#include <hip/hip_bf16.h>
#include <stdint.h>

namespace {

constexpr int Bx = 4, Tx = 2048, Cx = 1024, Hx = 16, Dx = 64;
constexpr int Mx = Bx * Tx;  // 8192

typedef __attribute__((ext_vector_type(8))) short bf16x8;
typedef __attribute__((ext_vector_type(4))) float f32x4;

__device__ __forceinline__ float b2f(unsigned short u) {
  unsigned int v = ((unsigned int)u) << 16;
  return __builtin_bit_cast(float, v);
}
__device__ __forceinline__ unsigned short f2b(float f) {
  unsigned int v = __builtin_bit_cast(unsigned int, f);
  v += 0x7fffu + ((v >> 16) & 1u);
  return (unsigned short)(v >> 16);
}

// ---------------- convert fp32 -> bf16 (vectorized) ----------------
__global__ void ca_cvt(const float* __restrict__ src, unsigned short* __restrict__ dst, int n4) {
  int i = blockIdx.x * blockDim.x + threadIdx.x;
  int stride = gridDim.x * blockDim.x;
  for (; i < n4; i += stride) {
    float4 f = ((const float4*)src)[i];
    ushort4 o;
    o.x = f2b(f.x); o.y = f2b(f.y); o.z = f2b(f.z); o.w = f2b(f.w);
    ((ushort4*)dst)[i] = o;
  }
}

// ---------------- W (K x N) -> Wt (N x K) bf16 ----------------
__global__ void ca_wt(const float* __restrict__ W, unsigned short* __restrict__ Wt) {
  __shared__ float tile[32][33];
  int n0 = blockIdx.x * 32, k0 = blockIdx.y * 32;
  int j = threadIdx.x & 31, i = threadIdx.x >> 5;  // i in 0..7
#pragma unroll
  for (int r = 0; r < 4; ++r)
    tile[i + 8 * r][j] = W[(size_t)(k0 + i + 8 * r) * Cx + n0 + j];
  __syncthreads();
#pragma unroll
  for (int r = 0; r < 4; ++r)
    Wt[(size_t)(n0 + i + 8 * r) * Cx + k0 + j] = f2b(tile[j][i + 8 * r]);
}

// ---------------- RoPE cos/sin table ----------------
__global__ void ca_rtab(float* __restrict__ ct, float* __restrict__ st) {
  int idx = blockIdx.x * blockDim.x + threadIdx.x;  // < Tx*32
  int t = idx >> 5, i = idx & 31;
  float fr = expf((float)i * -0.29710775393471563f);  // -ln(10000)/31
  float a = (float)t * fr;
  ct[idx] = cosf(a);
  st[idx] = sinf(a);
}

// ---------------- GEMM: A (MxK bf16) x Bt (NxK bf16) + bias ----------------
// MODE 0: out bf16, N=3072 split into 3 consecutive M*1024 tensors (q,k,v)
// MODE 1: out fp32, single tensor
template <int MODE>
__global__ __launch_bounds__(256) void ca_gemm(
    const unsigned short* __restrict__ A, const unsigned short* __restrict__ Bt,
    const float* __restrict__ b0, const float* __restrict__ b1, const float* __restrict__ b2,
    void* __restrict__ out, int M, int N, int K) {
  __shared__ __align__(16) unsigned short Al[128][40];
  __shared__ __align__(16) unsigned short Bl[128][40];
  int tid = threadIdx.x;
  int w = tid >> 6, l = tid & 63;
  int m0 = blockIdx.x * 128, n0 = blockIdx.y * 128;
  int wm = (w >> 1) * 64, wn = (w & 1) * 64;
  f32x4 acc[4][4] = {};

  uint4 ra[2], rb[2];
  int sr = tid >> 2, sc = (tid & 3) * 8;
  auto loadT = [&](int kt) {
    int k0 = kt * 32;
#pragma unroll
    for (int it = 0; it < 2; ++it) {
      int r = it * 64 + sr;
      ra[it] = *(const uint4*)&A[(size_t)(m0 + r) * K + k0 + sc];
      rb[it] = *(const uint4*)&Bt[(size_t)(n0 + r) * K + k0 + sc];
    }
  };
  loadT(0);
  int lr = l & 15, lk8 = (l >> 4) * 8;
  int nk = K / 32;
  for (int kt = 0; kt < nk; ++kt) {
    __syncthreads();
#pragma unroll
    for (int it = 0; it < 2; ++it) {
      int r = it * 64 + sr;
      *(uint4*)&Al[r][sc] = ra[it];
      *(uint4*)&Bl[r][sc] = rb[it];
    }
    __syncthreads();
    if (kt + 1 < nk) loadT(kt + 1);
    bf16x8 af[4], bf[4];
#pragma unroll
    for (int mi = 0; mi < 4; ++mi) af[mi] = *(const bf16x8*)&Al[wm + mi * 16 + lr][lk8];
#pragma unroll
    for (int ni = 0; ni < 4; ++ni) bf[ni] = *(const bf16x8*)&Bl[wn + ni * 16 + lr][lk8];
#pragma unroll
    for (int mi = 0; mi < 4; ++mi)
#pragma unroll
      for (int ni = 0; ni < 4; ++ni)
        acc[mi][ni] = __builtin_amdgcn_mfma_f32_16x16x32_bf16(af[mi], bf[ni], acc[mi][ni], 0, 0, 0);
  }

  int lq4 = (l >> 4) * 4;
  if (MODE == 0) {
    int which = n0 >> 10;
    int nb = n0 & 1023;
    const float* bias = which == 0 ? b0 : (which == 1 ? b1 : b2);
    unsigned short* o = (unsigned short*)out + (size_t)which * M * 1024;
#pragma unroll
    for (int mi = 0; mi < 4; ++mi)
#pragma unroll
      for (int ni = 0; ni < 4; ++ni) {
        int ncol = nb + wn + ni * 16 + lr;
        float bv = bias[ncol];
#pragma unroll
        for (int rg = 0; rg < 4; ++rg) {
          int m = m0 + wm + mi * 16 + lq4 + rg;
          o[(size_t)m * 1024 + ncol] = f2b(acc[mi][ni][rg] + bv);
        }
      }
  } else {
    float* o = (float*)out;
#pragma unroll
    for (int mi = 0; mi < 4; ++mi)
#pragma unroll
      for (int ni = 0; ni < 4; ++ni) {
        int ncol = n0 + wn + ni * 16 + lr;
        float bv = b0[ncol];
#pragma unroll
        for (int rg = 0; rg < 4; ++rg) {
          int m = m0 + wm + mi * 16 + lq4 + rg;
          o[(size_t)m * N + ncol] = acc[mi][ni][rg] + bv;
        }
      }
  }
}

// ---------------- RoPE apply (in-place on q and k, bf16) ----------------
__global__ void ca_rope(unsigned short* __restrict__ q, unsigned short* __restrict__ k,
                        const float* __restrict__ ct, const float* __restrict__ st) {
  int p = blockIdx.x * blockDim.x + threadIdx.x;  // handles 8 elems (4 pairs)
  int e = p * 8;
  int col = e & (Cx - 1);
  int t = (e >> 10) & (Tx - 1);
  int j0 = (col & (Dx - 1)) >> 1;
  float c[4], s[4];
#pragma unroll
  for (int jj = 0; jj < 4; ++jj) {
    c[jj] = ct[t * 32 + j0 + jj];
    s[jj] = st[t * 32 + j0 + jj];
  }
  {
    uint4 v = *(uint4*)&q[e];
    unsigned short* u = (unsigned short*)&v;
#pragma unroll
    for (int pr = 0; pr < 4; ++pr) {
      float xr = b2f(u[2 * pr]), xi = b2f(u[2 * pr + 1]);
      u[2 * pr] = f2b(xr * c[pr] - xi * s[pr]);
      u[2 * pr + 1] = f2b(xr * s[pr] + xi * c[pr]);
    }
    *(uint4*)&q[e] = v;
  }
  {
    uint4 v = *(uint4*)&k[e];
    unsigned short* u = (unsigned short*)&v;
#pragma unroll
    for (int pr = 0; pr < 4; ++pr) {
      float xr = b2f(u[2 * pr]), xi = b2f(u[2 * pr + 1]);
      u[2 * pr] = f2b(xr * c[pr] - xi * s[pr]);
      u[2 * pr + 1] = f2b(xr * s[pr] + xi * c[pr]);
    }
    *(uint4*)&k[e] = v;
  }
}

// ---------------- V (B,T,C) -> vT (B,H,D,T) ----------------
__global__ void ca_vt(const unsigned short* __restrict__ v, unsigned short* __restrict__ vT) {
  __shared__ __align__(16) unsigned short tl[64][72];
  int t0 = blockIdx.x * 64;
  int bh = blockIdx.y;
  int b = bh >> 4, h = bh & 15;
  int tid = threadIdx.x;
  const unsigned short* vb = v + (size_t)b * Tx * Cx + h * Dx;
#pragma unroll
  for (int it = 0; it < 2; ++it) {
    int tt = it * 32 + (tid >> 3), d0 = (tid & 7) * 8;
    uint4 x = *(const uint4*)&vb[(size_t)(t0 + tt) * Cx + d0];
    unsigned short* u = (unsigned short*)&x;
#pragma unroll
    for (int jj = 0; jj < 8; ++jj) tl[d0 + jj][tt] = u[jj];
  }
  __syncthreads();
  unsigned short* o = vT + (size_t)bh * Dx * Tx;
#pragma unroll
  for (int it = 0; it < 2; ++it) {
    int d = it * 32 + (tid >> 3), tc = (tid & 7) * 8;
    *(uint4*)&o[(size_t)d * Tx + t0 + tc] = *(const uint4*)&tl[d][tc];
  }
}

// ---------------- causal flash attention ----------------
__global__ __launch_bounds__(256) void ca_attn(
    const unsigned short* __restrict__ q, const unsigned short* __restrict__ k,
    const unsigned short* __restrict__ vT, unsigned short* __restrict__ y) {
  __shared__ __align__(16) unsigned short Kl[32][72];
  __shared__ __align__(16) unsigned short Vl[64][40];
  __shared__ __align__(16) unsigned short Pl[4][16][40];
  int tid = threadIdx.x, w = tid >> 6, l = tid & 63;
  int qt = (int)(gridDim.x - 1 - blockIdx.x);  // heavy tiles first
  int bh = blockIdx.y, b = bh >> 4, h = bh & 15;
  const unsigned short* qp = q + (size_t)b * Tx * Cx + h * Dx;
  const unsigned short* kp = k + (size_t)b * Tx * Cx + h * Dx;
  const unsigned short* vp = vT + (size_t)bh * Dx * Tx;
  int qbase = qt * 64 + w * 16;
  int lr = l & 15, lk8 = (l >> 4) * 8, lq4 = (l >> 4) * 4;

  bf16x8 qf[2];
  qf[0] = *(const bf16x8*)&qp[(size_t)(qbase + lr) * Cx + lk8];
  qf[1] = *(const bf16x8*)&qp[(size_t)(qbase + lr) * Cx + 32 + lk8];

  f32x4 oa[4] = {};
  float mrun[4], lrun[4];
#pragma unroll
  for (int rg = 0; rg < 4; ++rg) { mrun[rg] = -__builtin_inff(); lrun[rg] = 0.f; }

  int nt = 2 * (qt + 1);
  int ks = tid >> 3, kd = (tid & 7) * 8;  // K stage: row s, col d
  int vd = tid >> 2, vs = (tid & 3) * 8;  // V stage: row d, col s
  uint4 rk, rv;
  auto loadKV = [&](int t) {
    int s0 = t * 32;
    rk = *(const uint4*)&kp[(size_t)(s0 + ks) * Cx + kd];
    rv = *(const uint4*)&vp[(size_t)vd * Tx + s0 + vs];
  };
  loadKV(0);
  constexpr float L2E = 1.4426950408889634f;

  for (int t = 0; t < nt; ++t) {
    __syncthreads();
    *(uint4*)&Kl[ks][kd] = rk;
    *(uint4*)&Vl[vd][vs] = rv;
    __syncthreads();
    if (t + 1 < nt) loadKV(t + 1);

    // QK^T (16 q-rows x 32 s-cols), K reduction over D=64
    f32x4 sa[2];
#pragma unroll
    for (int si = 0; si < 2; ++si) {
      bf16x8 kf0 = *(const bf16x8*)&Kl[si * 16 + lr][lk8];
      bf16x8 kf1 = *(const bf16x8*)&Kl[si * 16 + lr][32 + lk8];
      f32x4 z = {0.f, 0.f, 0.f, 0.f};
      z = __builtin_amdgcn_mfma_f32_16x16x32_bf16(qf[0], kf0, z, 0, 0, 0);
      z = __builtin_amdgcn_mfma_f32_16x16x32_bf16(qf[1], kf1, z, 0, 0, 0);
      sa[si] = z;
    }
    int s0 = t * 32;
    float pm[4];
#pragma unroll
    for (int rg = 0; rg < 4; ++rg) {
      int qrow = qbase + lq4 + rg;
      float v0 = sa[0][rg] * 0.125f, v1 = sa[1][rg] * 0.125f;
      if (s0 + lr > qrow) v0 = -__builtin_inff();
      if (s0 + 16 + lr > qrow) v1 = -__builtin_inff();
      sa[0][rg] = v0; sa[1][rg] = v1;
      pm[rg] = fmaxf(v0, v1);
    }
#pragma unroll
    for (int off = 1; off < 16; off <<= 1)
#pragma unroll
      for (int rg = 0; rg < 4; ++rg) pm[rg] = fmaxf(pm[rg], __shfl_xor(pm[rg], off));

    float al[4];
#pragma unroll
    for (int rg = 0; rg < 4; ++rg) {
      float mn = fmaxf(mrun[rg], pm[rg]);
      al[rg] = exp2f((mrun[rg] - mn) * L2E);
      mrun[rg] = mn;
    }
    float ps[4];
#pragma unroll
    for (int rg = 0; rg < 4; ++rg) {
      float p0 = exp2f((sa[0][rg] - mrun[rg]) * L2E);
      float p1 = exp2f((sa[1][rg] - mrun[rg]) * L2E);
      Pl[w][lq4 + rg][lr] = f2b(p0);
      Pl[w][lq4 + rg][16 + lr] = f2b(p1);
      ps[rg] = p0 + p1;
    }
#pragma unroll
    for (int off = 1; off < 16; off <<= 1)
#pragma unroll
      for (int rg = 0; rg < 4; ++rg) ps[rg] += __shfl_xor(ps[rg], off);
#pragma unroll
    for (int rg = 0; rg < 4; ++rg) lrun[rg] = lrun[rg] * al[rg] + ps[rg];
#pragma unroll
    for (int di = 0; di < 4; ++di)
#pragma unroll
      for (int rg = 0; rg < 4; ++rg) oa[di][rg] *= al[rg];

    // PV: A = P (16x32), B = V^T tile rows d, K reduction over s=32
    bf16x8 pa = *(const bf16x8*)&Pl[w][lr][lk8];
#pragma unroll
    for (int di = 0; di < 4; ++di) {
      bf16x8 vf = *(const bf16x8*)&Vl[di * 16 + lr][lk8];
      oa[di] = __builtin_amdgcn_mfma_f32_16x16x32_bf16(pa, vf, oa[di], 0, 0, 0);
    }
  }

  unsigned short* yp = y + (size_t)b * Tx * Cx + h * Dx;
#pragma unroll
  for (int di = 0; di < 4; ++di)
#pragma unroll
    for (int rg = 0; rg < 4; ++rg) {
      int qrow = qbase + lq4 + rg;
      yp[(size_t)qrow * Cx + di * 16 + lr] = f2b(oa[di][rg] / lrun[rg]);
    }
}

}  // namespace

extern "C" void kernel_launch(void* const* d_in, const int* in_sizes, int n_in,
                              void* d_out, int out_size, void* d_ws, size_t ws_size,
                              hipStream_t stream) {
  const float* x = (const float*)d_in[0];
  const float* Wq = (const float*)d_in[1];
  const float* bq = (const float*)d_in[2];
  const float* Wk = (const float*)d_in[3];
  const float* bk = (const float*)d_in[4];
  const float* Wv = (const float*)d_in[5];
  const float* bv = (const float*)d_in[6];
  const float* Wp = (const float*)d_in[7];
  const float* bp = (const float*)d_in[8];

  unsigned short* xb = (unsigned short*)d_ws;                 // 8192*1024
  unsigned short* wt = xb + (size_t)Mx * Cx;                  // 4 * 1024*1024 (WqT,WkT,WvT,WpT)
  float* ct = (float*)(wt + (size_t)4 * Cx * Cx);             // 2048*32
  float* st = ct + Tx * 32;
  unsigned short* qb = (unsigned short*)(st + Tx * 32);       // q,k,v consecutive (split3 GEMM out)
  unsigned short* kb = qb + (size_t)Mx * Cx;
  unsigned short* vb = kb + (size_t)Mx * Cx;
  unsigned short* vT = vb + (size_t)Mx * Cx;
  unsigned short* yb = vT + (size_t)Mx * Cx;

  ca_cvt<<<dim3(2048), dim3(256), 0, stream>>>(x, xb, Mx * Cx / 4);
  ca_wt<<<dim3(32, 32), dim3(256), 0, stream>>>(Wq, wt + (size_t)0 * Cx * Cx);
  ca_wt<<<dim3(32, 32), dim3(256), 0, stream>>>(Wk, wt + (size_t)1 * Cx * Cx);
  ca_wt<<<dim3(32, 32), dim3(256), 0, stream>>>(Wv, wt + (size_t)2 * Cx * Cx);
  ca_wt<<<dim3(32, 32), dim3(256), 0, stream>>>(Wp, wt + (size_t)3 * Cx * Cx);
  ca_rtab<<<dim3(Tx * 32 / 256), dim3(256), 0, stream>>>(ct, st);

  ca_gemm<0><<<dim3(64, 24), dim3(256), 0, stream>>>(xb, wt, bq, bk, bv, qb, Mx, 3072, Cx);
  ca_rope<<<dim3(Mx * Cx / 8 / 256), dim3(256), 0, stream>>>(qb, kb, ct, st);
  ca_vt<<<dim3(Tx / 64, Bx * Hx), dim3(256), 0, stream>>>(vb, vT);
  ca_attn<<<dim3(Tx / 64, Bx * Hx), dim3(256), 0, stream>>>(qb, kb, vT, yb);
  ca_gemm<1><<<dim3(64, 8), dim3(256), 0, stream>>>(yb, wt + (size_t)3 * Cx * Cx, bp,
                                                    nullptr, nullptr, d_out, Mx, Cx, Cx);
}

// Round 2
// 274.935 us; speedup vs baseline: 2.3662x; 2.3662x over previous
//
#include <hip/hip_runtime.h>
#include <hip/hip_bf16.h>
#include <stdint.h>

namespace {

constexpr int Bx = 4, Tx = 2048, Cx = 1024, Hx = 16, Dx = 64;
constexpr int Mx = Bx * Tx;  // 8192

typedef __attribute__((ext_vector_type(8))) short bf16x8;
typedef __attribute__((ext_vector_type(4))) float f32x4;
typedef __attribute__((ext_vector_type(16))) float f32x16;

__device__ __forceinline__ float b2f(unsigned short u) {
  unsigned int v = ((unsigned int)u) << 16;
  return __builtin_bit_cast(float, v);
}
__device__ __forceinline__ unsigned short f2b(float f) {
  unsigned int v = __builtin_bit_cast(unsigned int, f);
  v += 0x7fffu + ((v >> 16) & 1u);
  return (unsigned short)(v >> 16);
}

#define GLD16(g, lp) __builtin_amdgcn_global_load_lds(                     \
    (__attribute__((address_space(1))) void*)(g),                          \
    (__attribute__((address_space(3))) void*)(lp), 16, 0, 0)

// ---------------- convert fp32 -> bf16 (vectorized) ----------------
__global__ void ca_cvt(const float* __restrict__ src, unsigned short* __restrict__ dst, int n4) {
  int i = blockIdx.x * blockDim.x + threadIdx.x;
  int stride = gridDim.x * blockDim.x;
  for (; i < n4; i += stride) {
    float4 f = ((const float4*)src)[i];
    ushort4 o;
    o.x = f2b(f.x); o.y = f2b(f.y); o.z = f2b(f.z); o.w = f2b(f.w);
    ((ushort4*)dst)[i] = o;
  }
}

// ---------------- W (K x N) -> Wt (N x K) bf16 ----------------
__global__ void ca_wt(const float* __restrict__ W, unsigned short* __restrict__ Wt) {
  __shared__ float tile[32][33];
  int n0 = blockIdx.x * 32, k0 = blockIdx.y * 32;
  int j = threadIdx.x & 31, i = threadIdx.x >> 5;  // i in 0..7
#pragma unroll
  for (int r = 0; r < 4; ++r)
    tile[i + 8 * r][j] = W[(size_t)(k0 + i + 8 * r) * Cx + n0 + j];
  __syncthreads();
#pragma unroll
  for (int r = 0; r < 4; ++r)
    Wt[(size_t)(n0 + i + 8 * r) * Cx + k0 + j] = f2b(tile[j][i + 8 * r]);
}

// ---------------- RoPE cos/sin table ----------------
__global__ void ca_rtab(float* __restrict__ ct, float* __restrict__ st) {
  int idx = blockIdx.x * blockDim.x + threadIdx.x;  // < Tx*32
  int t = idx >> 5, i = idx & 31;
  float fr = expf((float)i * -0.29710775393471563f);  // -ln(10000)/31
  float a = (float)t * fr;
  ct[idx] = cosf(a);
  st[idx] = sinf(a);
}

// ---------------- GEMM: A (MxK bf16) x Bt (NxK bf16) + bias ----------------
// m97 structure: 128x128 tile, BK=32, global_load_lds width-16, 2-barrier loop.
// MODE 0: out bf16, N=3072 split into 3 consecutive M*1024 tensors (q,k,v)
// MODE 1: out fp32, single tensor
template <int MODE>
__global__ __launch_bounds__(256) void ca_gemm(
    const unsigned short* __restrict__ A, const unsigned short* __restrict__ Bt,
    const float* __restrict__ b0, const float* __restrict__ b1, const float* __restrict__ b2,
    void* __restrict__ out, int M, int N, int K) {
  __shared__ __align__(16) unsigned short Al[128 * 32];
  __shared__ __align__(16) unsigned short Bl[128 * 32];
  int tid = threadIdx.x;
  int w = tid >> 6, l = tid & 63;
  int m0 = blockIdx.x * 128, n0 = blockIdx.y * 128;
  int wm = (w >> 1) * 64, wn = (w & 1) * 64;
  f32x4 acc[4][4] = {};

  int lr = l & 15, lk8 = (l >> 4) * 8;
  int srow = w * 32 + (l >> 2), scol = (l & 3) * 8;
  const unsigned short* ga0 = A + (size_t)(m0 + srow) * K + scol;
  const unsigned short* gb0 = Bt + (size_t)(n0 + srow) * K + scol;
  unsigned short* la = &Al[w * 1024];
  unsigned short* lb = &Bl[w * 1024];
  int nk = K / 32;
  for (int kt = 0; kt < nk; ++kt) {
    const unsigned short* ga = ga0 + kt * 32;
    const unsigned short* gb = gb0 + kt * 32;
    GLD16(ga, la);
    GLD16(ga + (size_t)16 * K, la + 512);
    GLD16(gb, lb);
    GLD16(gb + (size_t)16 * K, lb + 512);
    __syncthreads();  // vmcnt(0) drain + sync -> tile visible
    bf16x8 af[4], bfr[4];
#pragma unroll
    for (int mi = 0; mi < 4; ++mi) af[mi] = *(const bf16x8*)&Al[(wm + mi * 16 + lr) * 32 + lk8];
#pragma unroll
    for (int ni = 0; ni < 4; ++ni) bfr[ni] = *(const bf16x8*)&Bl[(wn + ni * 16 + lr) * 32 + lk8];
#pragma unroll
    for (int mi = 0; mi < 4; ++mi)
#pragma unroll
      for (int ni = 0; ni < 4; ++ni)
        acc[mi][ni] = __builtin_amdgcn_mfma_f32_16x16x32_bf16(af[mi], bfr[ni], acc[mi][ni], 0, 0, 0);
    __syncthreads();  // all waves done reading before next stage
  }

  int lq4 = (l >> 4) * 4;
  if (MODE == 0) {
    int which = n0 >> 10;
    int nb = n0 & 1023;
    const float* bias = which == 0 ? b0 : (which == 1 ? b1 : b2);
    unsigned short* o = (unsigned short*)out + (size_t)which * M * 1024;
#pragma unroll
    for (int mi = 0; mi < 4; ++mi)
#pragma unroll
      for (int ni = 0; ni < 4; ++ni) {
        int ncol = nb + wn + ni * 16 + lr;
        float bv = bias[ncol];
#pragma unroll
        for (int rg = 0; rg < 4; ++rg) {
          int m = m0 + wm + mi * 16 + lq4 + rg;
          o[(size_t)m * 1024 + ncol] = f2b(acc[mi][ni][rg] + bv);
        }
      }
  } else {
    float* o = (float*)out;
#pragma unroll
    for (int mi = 0; mi < 4; ++mi)
#pragma unroll
      for (int ni = 0; ni < 4; ++ni) {
        int ncol = n0 + wn + ni * 16 + lr;
        float bv = b0[ncol];
#pragma unroll
        for (int rg = 0; rg < 4; ++rg) {
          int m = m0 + wm + mi * 16 + lq4 + rg;
          o[(size_t)m * N + ncol] = acc[mi][ni][rg] + bv;
        }
      }
  }
}

// ---------------- RoPE apply (in-place on q and k, bf16) ----------------
__global__ void ca_rope(unsigned short* __restrict__ q, unsigned short* __restrict__ k,
                        const float* __restrict__ ct, const float* __restrict__ st) {
  int p = blockIdx.x * blockDim.x + threadIdx.x;  // handles 8 elems (4 pairs)
  int e = p * 8;
  int col = e & (Cx - 1);
  int t = (e >> 10) & (Tx - 1);
  int j0 = (col & (Dx - 1)) >> 1;
  float c[4], s[4];
#pragma unroll
  for (int jj = 0; jj < 4; ++jj) {
    c[jj] = ct[t * 32 + j0 + jj];
    s[jj] = st[t * 32 + j0 + jj];
  }
  {
    uint4 v = *(uint4*)&q[e];
    unsigned short* u = (unsigned short*)&v;
#pragma unroll
    for (int pr = 0; pr < 4; ++pr) {
      float xr = b2f(u[2 * pr]), xi = b2f(u[2 * pr + 1]);
      u[2 * pr] = f2b(xr * c[pr] - xi * s[pr]);
      u[2 * pr + 1] = f2b(xr * s[pr] + xi * c[pr]);
    }
    *(uint4*)&q[e] = v;
  }
  {
    uint4 v = *(uint4*)&k[e];
    unsigned short* u = (unsigned short*)&v;
#pragma unroll
    for (int pr = 0; pr < 4; ++pr) {
      float xr = b2f(u[2 * pr]), xi = b2f(u[2 * pr + 1]);
      u[2 * pr] = f2b(xr * c[pr] - xi * s[pr]);
      u[2 * pr + 1] = f2b(xr * s[pr] + xi * c[pr]);
    }
    *(uint4*)&k[e] = v;
  }
}

// ---------------- V (B,T,C) -> vT (B,H,D,T) ----------------
__global__ void ca_vt(const unsigned short* __restrict__ v, unsigned short* __restrict__ vT) {
  __shared__ __align__(16) unsigned short tl[64][72];
  int t0 = blockIdx.x * 64;
  int bh = blockIdx.y;
  int b = bh >> 4, h = bh & 15;
  int tid = threadIdx.x;
  const unsigned short* vb = v + (size_t)b * Tx * Cx + h * Dx;
#pragma unroll
  for (int it = 0; it < 2; ++it) {
    int tt = it * 32 + (tid >> 3), d0 = (tid & 7) * 8;
    uint4 x = *(const uint4*)&vb[(size_t)(t0 + tt) * Cx + d0];
    unsigned short* u = (unsigned short*)&x;
#pragma unroll
    for (int jj = 0; jj < 8; ++jj) tl[d0 + jj][tt] = u[jj];
  }
  __syncthreads();
  unsigned short* o = vT + (size_t)bh * Dx * Tx;
#pragma unroll
  for (int it = 0; it < 2; ++it) {
    int d = it * 32 + (tid >> 3), tc = (tid & 7) * 8;
    *(uint4*)&o[(size_t)d * Tx + t0 + tc] = *(const uint4*)&tl[d][tc];
  }
}

// ---------------- causal flash attention (swapped QK^T, barrier-free loop) ---
// Grid: (bh=64, qt=16). Block: 4 waves; wave w owns q rows [qt*128+w*32, +32).
// Per 32-kv tile: S^T = mfma(K,Q) (lane owns all kv for one q col), in-register
// online softmax (1 shfl per reduce), P repacked via shfl_xor(32) into the PV
// B-fragment; O^T accumulated in 32 f32 regs; LDS only for the final transpose.
__global__ __launch_bounds__(256) void ca_attn(
    const unsigned short* __restrict__ q, const unsigned short* __restrict__ k,
    const unsigned short* __restrict__ vT, unsigned short* __restrict__ y) {
  __shared__ uint32_t els[4][32][33];
  int tid = threadIdx.x, w = tid >> 6, l = tid & 63;
  int bh = blockIdx.x;                              // XCD = id%8 = bh%8 -> KV L2-pinned
  int qt = (int)gridDim.y - 1 - (int)blockIdx.y;    // heavy q-tiles first
  int b = bh >> 4, h = bh & 15;
  const unsigned short* qp = q + (size_t)b * Tx * Cx + h * Dx;
  const unsigned short* kp = k + (size_t)b * Tx * Cx + h * Dx;
  const unsigned short* vp = vT + (size_t)bh * Dx * Tx;
  int qbase = qt * 128 + w * 32;
  int lo = l & 31, hi = l >> 5;

  bf16x8 qf[4];
  {
    const unsigned short* qr = qp + (size_t)(qbase + lo) * Cx + hi * 8;
#pragma unroll
    for (int c = 0; c < 4; ++c) qf[c] = *(const bf16x8*)(qr + c * 16);
  }

  f32x16 acc0 = {}, acc1 = {};
  float m = -__builtin_inff(), lsum = 0.f;
  int nt = qt * 4 + w + 1;

  uint4 rk[4], rv[4];
  const unsigned short* kr0 = kp + (size_t)lo * Cx + hi * 8;
  const unsigned short* vr0 = vp + (size_t)lo * Tx + hi * 8;
  auto loadK = [&](int t) {
    const unsigned short* kr = kr0 + (size_t)t * 32 * Cx;
#pragma unroll
    for (int c = 0; c < 4; ++c) rk[c] = *(const uint4*)(kr + c * 16);
  };
  auto loadV = [&](int t) {
#pragma unroll
    for (int dc = 0; dc < 2; ++dc)
#pragma unroll
      for (int kc = 0; kc < 2; ++kc)
        rv[dc * 2 + kc] = *(const uint4*)(vr0 + (size_t)dc * 32 * Tx + t * 32 + kc * 16);
  };
  loadK(0);
  loadV(0);
  constexpr float SC = 0.18033688011112042f;  // 0.125 * log2(e)

  for (int t = 0; t < nt; ++t) {
    bf16x8 kf[4], vf[4];
#pragma unroll
    for (int c = 0; c < 4; ++c) kf[c] = __builtin_bit_cast(bf16x8, rk[c]);
#pragma unroll
    for (int c = 0; c < 4; ++c) vf[c] = __builtin_bit_cast(bf16x8, rv[c]);
    if (t + 1 < nt) { loadK(t + 1); loadV(t + 1); }  // prefetch under softmax

    f32x16 s = {};
#pragma unroll
    for (int c = 0; c < 4; ++c)
      s = __builtin_amdgcn_mfma_f32_32x32x16_bf16(kf[c], qf[c], s, 0, 0, 0);

    float tv[16];
#pragma unroll
    for (int r = 0; r < 16; ++r) tv[r] = s[r] * SC;
    if (t == nt - 1) {  // diagonal tile is exactly the last tile per wave
#pragma unroll
      for (int r = 0; r < 16; ++r) {
        int kvr = (r & 3) + 8 * (r >> 2) + 4 * hi;
        if (kvr > lo) tv[r] = -3.0e38f;
      }
    }
    float pmax = tv[0];
#pragma unroll
    for (int r = 1; r < 16; ++r) pmax = fmaxf(pmax, tv[r]);
    pmax = fmaxf(pmax, __shfl_xor(pmax, 32));
    if (!__all(pmax - m <= 11.0f)) {  // defer-max (T13), log2 units
      float mn = fmaxf(m, pmax);
      float al = exp2f(m - mn);
      m = mn;
      lsum *= al;
#pragma unroll
      for (int r = 0; r < 16; ++r) { acc0[r] *= al; acc1[r] *= al; }
    }
    float p[16];
    float ps = 0.f;
#pragma unroll
    for (int r = 0; r < 16; ++r) {
      p[r] = exp2f(tv[r] - m);
      ps += p[r];
    }
    ps += __shfl_xor(ps, 32);
    lsum += ps;

    // pack P (f32 x16) -> bf16 B-fragments for PV; kv redistribution via lane^32
    uint32_t pk[8];
#pragma unroll
    for (int i = 0; i < 8; ++i)
      pk[i] = (uint32_t)f2b(p[2 * i]) | ((uint32_t)f2b(p[2 * i + 1]) << 16);
    uint32_t sw[8];
#pragma unroll
    for (int i = 0; i < 8; ++i) sw[i] = (uint32_t)__shfl_xor((int)pk[i], 32);
    uint4 xw, yw;
    xw.x = hi ? sw[2] : pk[0];
    xw.y = hi ? sw[3] : pk[1];
    xw.z = hi ? pk[2] : sw[0];
    xw.w = hi ? pk[3] : sw[1];
    yw.x = hi ? sw[6] : pk[4];
    yw.y = hi ? sw[7] : pk[5];
    yw.z = hi ? pk[6] : sw[4];
    yw.w = hi ? pk[7] : sw[5];
    bf16x8 PB0 = __builtin_bit_cast(bf16x8, xw);
    bf16x8 PB1 = __builtin_bit_cast(bf16x8, yw);
    acc0 = __builtin_amdgcn_mfma_f32_32x32x16_bf16(vf[0], PB0, acc0, 0, 0, 0);
    acc0 = __builtin_amdgcn_mfma_f32_32x32x16_bf16(vf[1], PB1, acc0, 0, 0, 0);
    acc1 = __builtin_amdgcn_mfma_f32_32x32x16_bf16(vf[2], PB0, acc1, 0, 0, 0);
    acc1 = __builtin_amdgcn_mfma_f32_32x32x16_bf16(vf[3], PB1, acc1, 0, 0, 0);
  }

  // epilogue: O^T (d-major regs) -> LDS transpose -> coalesced row writes
  float rl = 1.0f / lsum;
#pragma unroll
  for (int dc = 0; dc < 2; ++dc) {
    f32x16 a = dc ? acc1 : acc0;
#pragma unroll
    for (int i = 0; i < 8; ++i) {
      uint32_t pkd = (uint32_t)f2b(a[2 * i] * rl) | ((uint32_t)f2b(a[2 * i + 1] * rl) << 16);
      int d2 = (i & 1) + 4 * (i >> 1) + 2 * hi + dc * 16;
      els[w][lo][d2] = pkd;
    }
  }
  __syncthreads();
  unsigned short* yp = y + (size_t)b * Tx * Cx + h * Dx;
#pragma unroll
  for (int pp = 0; pp < 16; ++pp) {
    int qr = 2 * pp + hi;
    uint32_t val = els[w][qr][lo];
    *(uint32_t*)(yp + (size_t)(qbase + qr) * Cx + lo * 2) = val;
  }
}

}  // namespace

extern "C" void kernel_launch(void* const* d_in, const int* in_sizes, int n_in,
                              void* d_out, int out_size, void* d_ws, size_t ws_size,
                              hipStream_t stream) {
  const float* x = (const float*)d_in[0];
  const float* Wq = (const float*)d_in[1];
  const float* bq = (const float*)d_in[2];
  const float* Wk = (const float*)d_in[3];
  const float* bk = (const float*)d_in[4];
  const float* Wv = (const float*)d_in[5];
  const float* bv = (const float*)d_in[6];
  const float* Wp = (const float*)d_in[7];
  const float* bp = (const float*)d_in[8];

  unsigned short* xb = (unsigned short*)d_ws;                 // 8192*1024
  unsigned short* wt = xb + (size_t)Mx * Cx;                  // 4 * 1024*1024 (WqT,WkT,WvT,WpT)
  float* ct = (float*)(wt + (size_t)4 * Cx * Cx);             // 2048*32
  float* st = ct + Tx * 32;
  unsigned short* qb = (unsigned short*)(st + Tx * 32);       // q,k,v consecutive (split3 GEMM out)
  unsigned short* kb = qb + (size_t)Mx * Cx;
  unsigned short* vb = kb + (size_t)Mx * Cx;
  unsigned short* vT = vb + (size_t)Mx * Cx;
  unsigned short* yb = vT + (size_t)Mx * Cx;

  ca_cvt<<<dim3(2048), dim3(256), 0, stream>>>(x, xb, Mx * Cx / 4);
  ca_wt<<<dim3(32, 32), dim3(256), 0, stream>>>(Wq, wt + (size_t)0 * Cx * Cx);
  ca_wt<<<dim3(32, 32), dim3(256), 0, stream>>>(Wk, wt + (size_t)1 * Cx * Cx);
  ca_wt<<<dim3(32, 32), dim3(256), 0, stream>>>(Wv, wt + (size_t)2 * Cx * Cx);
  ca_wt<<<dim3(32, 32), dim3(256), 0, stream>>>(Wp, wt + (size_t)3 * Cx * Cx);
  ca_rtab<<<dim3(Tx * 32 / 256), dim3(256), 0, stream>>>(ct, st);

  ca_gemm<0><<<dim3(64, 24), dim3(256), 0, stream>>>(xb, wt, bq, bk, bv, qb, Mx, 3072, Cx);
  ca_rope<<<dim3(Mx * Cx / 8 / 256), dim3(256), 0, stream>>>(qb, kb, ct, st);
  ca_vt<<<dim3(Tx / 64, Bx * Hx), dim3(256), 0, stream>>>(vb, vT);
  ca_attn<<<dim3(64, 16), dim3(256), 0, stream>>>(qb, kb, vT, yb);
  ca_gemm<1><<<dim3(64, 8), dim3(256), 0, stream>>>(yb, wt + (size_t)3 * Cx * Cx, bp,
                                                    nullptr, nullptr, d_out, Mx, Cx, Cx);
}

// Round 5
// 274.739 us; speedup vs baseline: 2.3678x; 1.0007x over previous
//
#include <hip/hip_runtime.h>
#include <hip/hip_bf16.h>
#include <stdint.h>

namespace {

constexpr int Bx = 4, Tx = 2048, Cx = 1024, Hx = 16, Dx = 64;
constexpr int Mx = Bx * Tx;  // 8192

typedef __attribute__((ext_vector_type(8))) short bf16x8;
typedef __attribute__((ext_vector_type(4))) float f32x4;
typedef __attribute__((ext_vector_type(16))) float f32x16;
typedef __attribute__((ext_vector_type(2))) unsigned int u32x2;

__device__ __forceinline__ float b2f(unsigned short u) {
  unsigned int v = ((unsigned int)u) << 16;
  return __builtin_bit_cast(float, v);
}
__device__ __forceinline__ unsigned short f2b(float f) {
  unsigned int v = __builtin_bit_cast(unsigned int, f);
  v += 0x7fffu + ((v >> 16) & 1u);
  return (unsigned short)(v >> 16);
}
__device__ __forceinline__ uint32_t pkbf(float a, float b) {
  __hip_bfloat162 h = __float22bfloat162_rn(float2{a, b});
  uint32_t r;
  __builtin_memcpy(&r, &h, 4);  // __hip_bfloat162 not trivially copyable -> no bit_cast
  return r;
}
// permlane32_swap via builtin (compiler handles VALU->permlane hazards; the
// inline-asm version read stale regs -> NaN):
//   a_new[i] = i<32 ? a[i] : b[i-32];  b_new[i] = i<32 ? a[i+32] : b[i]
__device__ __forceinline__ void pl32swap(uint32_t& a, uint32_t& b) {
  u32x2 r = __builtin_amdgcn_permlane32_swap(a, b, false, false);
  a = r[0];
  b = r[1];
}
__device__ __forceinline__ float xhalf_max(float x) {
  uint32_t a = __builtin_bit_cast(uint32_t, x), b = a;
  pl32swap(a, b);
  return fmaxf(__builtin_bit_cast(float, a), __builtin_bit_cast(float, b));
}
__device__ __forceinline__ float xhalf_sum(float x) {
  uint32_t a = __builtin_bit_cast(uint32_t, x), b = a;
  pl32swap(a, b);
  return __builtin_bit_cast(float, a) + __builtin_bit_cast(float, b);
}

#define GLD16(g, lp) __builtin_amdgcn_global_load_lds(                     \
    (__attribute__((address_space(1))) void*)(g),                          \
    (__attribute__((address_space(3))) void*)(lp), 16, 0, 0)

// ---------------- convert fp32 -> bf16 (vectorized) ----------------
__global__ void ca_cvt(const float* __restrict__ src, unsigned short* __restrict__ dst, int n4) {
  int i = blockIdx.x * blockDim.x + threadIdx.x;
  int stride = gridDim.x * blockDim.x;
  for (; i < n4; i += stride) {
    float4 f = ((const float4*)src)[i];
    ushort4 o;
    o.x = f2b(f.x); o.y = f2b(f.y); o.z = f2b(f.z); o.w = f2b(f.w);
    ((ushort4*)dst)[i] = o;
  }
}

// ---------------- W (K x N) -> Wt (N x K) bf16 ----------------
__global__ void ca_wt(const float* __restrict__ W, unsigned short* __restrict__ Wt) {
  __shared__ float tile[32][33];
  int n0 = blockIdx.x * 32, k0 = blockIdx.y * 32;
  int j = threadIdx.x & 31, i = threadIdx.x >> 5;  // i in 0..7
#pragma unroll
  for (int r = 0; r < 4; ++r)
    tile[i + 8 * r][j] = W[(size_t)(k0 + i + 8 * r) * Cx + n0 + j];
  __syncthreads();
#pragma unroll
  for (int r = 0; r < 4; ++r)
    Wt[(size_t)(n0 + i + 8 * r) * Cx + k0 + j] = f2b(tile[j][i + 8 * r]);
}

// ---------------- RoPE cos/sin table ----------------
__global__ void ca_rtab(float* __restrict__ ct, float* __restrict__ st) {
  int idx = blockIdx.x * blockDim.x + threadIdx.x;  // < Tx*32
  int t = idx >> 5, i = idx & 31;
  float fr = expf((float)i * -0.29710775393471563f);  // -ln(10000)/31
  float a = (float)t * fr;
  ct[idx] = cosf(a);
  st[idx] = sinf(a);
}

// ---------------- GEMM: A (MxK bf16) x Bt (NxK bf16) + bias ----------------
// m97 structure: 128x128 tile, BK=32, global_load_lds width-16, 2-barrier loop.
template <int MODE>
__global__ __launch_bounds__(256) void ca_gemm(
    const unsigned short* __restrict__ A, const unsigned short* __restrict__ Bt,
    const float* __restrict__ b0, const float* __restrict__ b1, const float* __restrict__ b2,
    void* __restrict__ out, int M, int N, int K) {
  __shared__ __align__(16) unsigned short Al[128 * 32];
  __shared__ __align__(16) unsigned short Bl[128 * 32];
  int tid = threadIdx.x;
  int w = tid >> 6, l = tid & 63;
  int m0 = blockIdx.x * 128, n0 = blockIdx.y * 128;
  int wm = (w >> 1) * 64, wn = (w & 1) * 64;
  f32x4 acc[4][4] = {};

  int lr = l & 15, lk8 = (l >> 4) * 8;
  int srow = w * 32 + (l >> 2), scol = (l & 3) * 8;
  const unsigned short* ga0 = A + (size_t)(m0 + srow) * K + scol;
  const unsigned short* gb0 = Bt + (size_t)(n0 + srow) * K + scol;
  unsigned short* la = &Al[w * 1024];
  unsigned short* lb = &Bl[w * 1024];
  int nk = K / 32;
  for (int kt = 0; kt < nk; ++kt) {
    const unsigned short* ga = ga0 + kt * 32;
    const unsigned short* gb = gb0 + kt * 32;
    GLD16(ga, la);
    GLD16(ga + (size_t)16 * K, la + 512);
    GLD16(gb, lb);
    GLD16(gb + (size_t)16 * K, lb + 512);
    __syncthreads();
    bf16x8 af[4], bfr[4];
#pragma unroll
    for (int mi = 0; mi < 4; ++mi) af[mi] = *(const bf16x8*)&Al[(wm + mi * 16 + lr) * 32 + lk8];
#pragma unroll
    for (int ni = 0; ni < 4; ++ni) bfr[ni] = *(const bf16x8*)&Bl[(wn + ni * 16 + lr) * 32 + lk8];
#pragma unroll
    for (int mi = 0; mi < 4; ++mi)
#pragma unroll
      for (int ni = 0; ni < 4; ++ni)
        acc[mi][ni] = __builtin_amdgcn_mfma_f32_16x16x32_bf16(af[mi], bfr[ni], acc[mi][ni], 0, 0, 0);
    __syncthreads();
  }

  int lq4 = (l >> 4) * 4;
  if (MODE == 0) {
    int which = n0 >> 10;
    int nb = n0 & 1023;
    const float* bias = which == 0 ? b0 : (which == 1 ? b1 : b2);
    unsigned short* o = (unsigned short*)out + (size_t)which * M * 1024;
#pragma unroll
    for (int mi = 0; mi < 4; ++mi)
#pragma unroll
      for (int ni = 0; ni < 4; ++ni) {
        int ncol = nb + wn + ni * 16 + lr;
        float bv = bias[ncol];
#pragma unroll
        for (int rg = 0; rg < 4; ++rg) {
          int m = m0 + wm + mi * 16 + lq4 + rg;
          o[(size_t)m * 1024 + ncol] = f2b(acc[mi][ni][rg] + bv);
        }
      }
  } else {
    float* o = (float*)out;
#pragma unroll
    for (int mi = 0; mi < 4; ++mi)
#pragma unroll
      for (int ni = 0; ni < 4; ++ni) {
        int ncol = n0 + wn + ni * 16 + lr;
        float bv = b0[ncol];
#pragma unroll
        for (int rg = 0; rg < 4; ++rg) {
          int m = m0 + wm + mi * 16 + lq4 + rg;
          o[(size_t)m * N + ncol] = acc[mi][ni][rg] + bv;
        }
      }
  }
}

// ---------------- RoPE apply (in-place on q and k, bf16) ----------------
// Q is additionally pre-scaled by 0.125*log2(e) so attention scores come out
// of the QK^T MFMA directly in log2 domain (kills 16 mults/tile in attn).
__global__ void ca_rope(unsigned short* __restrict__ q, unsigned short* __restrict__ k,
                        const float* __restrict__ ct, const float* __restrict__ st) {
  constexpr float SC = 0.18033688011112042f;  // 0.125 * log2(e)
  int p = blockIdx.x * blockDim.x + threadIdx.x;  // handles 8 elems (4 pairs)
  int e = p * 8;
  int col = e & (Cx - 1);
  int t = (e >> 10) & (Tx - 1);
  int j0 = (col & (Dx - 1)) >> 1;
  float c[4], s[4];
#pragma unroll
  for (int jj = 0; jj < 4; ++jj) {
    c[jj] = ct[t * 32 + j0 + jj];
    s[jj] = st[t * 32 + j0 + jj];
  }
  {
    uint4 v = *(uint4*)&q[e];
    unsigned short* u = (unsigned short*)&v;
#pragma unroll
    for (int pr = 0; pr < 4; ++pr) {
      float xr = b2f(u[2 * pr]), xi = b2f(u[2 * pr + 1]);
      u[2 * pr] = f2b((xr * c[pr] - xi * s[pr]) * SC);
      u[2 * pr + 1] = f2b((xr * s[pr] + xi * c[pr]) * SC);
    }
    *(uint4*)&q[e] = v;
  }
  {
    uint4 v = *(uint4*)&k[e];
    unsigned short* u = (unsigned short*)&v;
#pragma unroll
    for (int pr = 0; pr < 4; ++pr) {
      float xr = b2f(u[2 * pr]), xi = b2f(u[2 * pr + 1]);
      u[2 * pr] = f2b(xr * c[pr] - xi * s[pr]);
      u[2 * pr + 1] = f2b(xr * s[pr] + xi * c[pr]);
    }
    *(uint4*)&k[e] = v;
  }
}

// ---------------- V (B,T,C) -> vT (B,H,D,T) ----------------
__global__ void ca_vt(const unsigned short* __restrict__ v, unsigned short* __restrict__ vT) {
  __shared__ __align__(16) unsigned short tl[64][72];
  int t0 = blockIdx.x * 64;
  int bh = blockIdx.y;
  int b = bh >> 4, h = bh & 15;
  int tid = threadIdx.x;
  const unsigned short* vb = v + (size_t)b * Tx * Cx + h * Dx;
#pragma unroll
  for (int it = 0; it < 2; ++it) {
    int tt = it * 32 + (tid >> 3), d0 = (tid & 7) * 8;
    uint4 x = *(const uint4*)&vb[(size_t)(t0 + tt) * Cx + d0];
    unsigned short* u = (unsigned short*)&x;
#pragma unroll
    for (int jj = 0; jj < 8; ++jj) tl[d0 + jj][tt] = u[jj];
  }
  __syncthreads();
  unsigned short* o = vT + (size_t)bh * Dx * Tx;
#pragma unroll
  for (int it = 0; it < 2; ++it) {
    int d = it * 32 + (tid >> 3), tc = (tid & 7) * 8;
    *(uint4*)&o[(size_t)d * Tx + t0 + tc] = *(const uint4*)&tl[d][tc];
  }
}

// ---------------- causal flash attention (swapped QK^T, VALU-dieted) --------
__global__ __launch_bounds__(256) void ca_attn(
    const unsigned short* __restrict__ q, const unsigned short* __restrict__ k,
    const unsigned short* __restrict__ vT, unsigned short* __restrict__ y) {
  __shared__ uint32_t els[4][32][33];
  int tid = threadIdx.x, w = tid >> 6, l = tid & 63;
  int bh = blockIdx.x;                              // XCD = id%8 = bh%8 -> KV L2-pinned
  int qt = (int)gridDim.y - 1 - (int)blockIdx.y;    // heavy q-tiles first
  int b = bh >> 4, h = bh & 15;
  const unsigned short* qp = q + (size_t)b * Tx * Cx + h * Dx;
  const unsigned short* kp = k + (size_t)b * Tx * Cx + h * Dx;
  const unsigned short* vp = vT + (size_t)bh * Dx * Tx;
  int qbase = qt * 128 + w * 32;
  int lo = l & 31, hi = l >> 5;

  bf16x8 qf[4];
  {
    const unsigned short* qr = qp + (size_t)(qbase + lo) * Cx + hi * 8;
#pragma unroll
    for (int c = 0; c < 4; ++c) qf[c] = *(const bf16x8*)(qr + c * 16);
  }

  f32x16 acc0 = {}, acc1 = {};
  float m = -__builtin_inff(), lsum = 0.f;
  int nt = qt * 4 + w + 1;

  uint4 rk[4], rv[4];
  const unsigned short* kr0 = kp + (size_t)lo * Cx + hi * 8;
  const unsigned short* vr0 = vp + (size_t)lo * Tx + hi * 8;
  auto loadK = [&](int t) {
    const unsigned short* kr = kr0 + (size_t)t * 32 * Cx;
#pragma unroll
    for (int c = 0; c < 4; ++c) rk[c] = *(const uint4*)(kr + c * 16);
  };
  auto loadV = [&](int t) {
#pragma unroll
    for (int dc = 0; dc < 2; ++dc)
#pragma unroll
      for (int kc = 0; kc < 2; ++kc)
        rv[dc * 2 + kc] = *(const uint4*)(vr0 + (size_t)dc * 32 * Tx + t * 32 + kc * 16);
  };
  loadK(0);
  loadV(0);

  for (int t = 0; t < nt; ++t) {
    bf16x8 kf[4], vf[4];
#pragma unroll
    for (int c = 0; c < 4; ++c) kf[c] = __builtin_bit_cast(bf16x8, rk[c]);
#pragma unroll
    for (int c = 0; c < 4; ++c) vf[c] = __builtin_bit_cast(bf16x8, rv[c]);
    if (t + 1 < nt) { loadK(t + 1); loadV(t + 1); }  // prefetch under softmax

    __builtin_amdgcn_s_setprio(1);
    f32x16 s = {};
#pragma unroll
    for (int c = 0; c < 4; ++c)
      s = __builtin_amdgcn_mfma_f32_32x32x16_bf16(kf[c], qf[c], s, 0, 0, 0);
    __builtin_amdgcn_s_setprio(0);

    // scores already in log2 domain (Q pre-scaled by 0.125*log2e in ca_rope)
    float tv[16];
#pragma unroll
    for (int r = 0; r < 16; ++r) tv[r] = s[r];
    if (t == nt - 1) {  // diagonal tile is exactly the last tile per wave
#pragma unroll
      for (int r = 0; r < 16; ++r) {
        int kvr = (r & 3) + 8 * (r >> 2) + 4 * hi;
        if (kvr > lo) tv[r] = -3.0e38f;
      }
    }
    // balanced max tree (fuses to v_max3)
    float mx[8];
#pragma unroll
    for (int r = 0; r < 8; ++r) mx[r] = fmaxf(tv[2 * r], tv[2 * r + 1]);
#pragma unroll
    for (int r = 0; r < 4; ++r) mx[r] = fmaxf(mx[2 * r], mx[2 * r + 1]);
    float pmax = fmaxf(fmaxf(mx[0], mx[1]), fmaxf(mx[2], mx[3]));
    pmax = xhalf_max(pmax);
    if (!__all(pmax - m <= 11.0f)) {  // defer-max (T13), log2 units
      float mn = fmaxf(m, pmax);
      float al = exp2f(m - mn);
      m = mn;
      lsum *= al;
#pragma unroll
      for (int r = 0; r < 16; ++r) { acc0[r] *= al; acc1[r] *= al; }
    }
    float p[16];
#pragma unroll
    for (int r = 0; r < 16; ++r) p[r] = exp2f(tv[r] - m);
    // balanced sum tree
    float sm[8];
#pragma unroll
    for (int r = 0; r < 8; ++r) sm[r] = p[2 * r] + p[2 * r + 1];
#pragma unroll
    for (int r = 0; r < 4; ++r) sm[r] = sm[2 * r] + sm[2 * r + 1];
    float ps = (sm[0] + sm[1]) + (sm[2] + sm[3]);
    lsum += xhalf_sum(ps);

    // pack P -> bf16 pairs; kv redistribution via 4 permlane32_swap
    uint32_t pk[8];
#pragma unroll
    for (int i = 0; i < 8; ++i) pk[i] = pkbf(p[2 * i], p[2 * i + 1]);
    pl32swap(pk[0], pk[2]);
    pl32swap(pk[1], pk[3]);
    pl32swap(pk[4], pk[6]);
    pl32swap(pk[5], pk[7]);
    uint4 xw{pk[0], pk[1], pk[2], pk[3]}, yw{pk[4], pk[5], pk[6], pk[7]};
    bf16x8 PB0 = __builtin_bit_cast(bf16x8, xw);
    bf16x8 PB1 = __builtin_bit_cast(bf16x8, yw);
    __builtin_amdgcn_s_setprio(1);
    acc0 = __builtin_amdgcn_mfma_f32_32x32x16_bf16(vf[0], PB0, acc0, 0, 0, 0);
    acc0 = __builtin_amdgcn_mfma_f32_32x32x16_bf16(vf[1], PB1, acc0, 0, 0, 0);
    acc1 = __builtin_amdgcn_mfma_f32_32x32x16_bf16(vf[2], PB0, acc1, 0, 0, 0);
    acc1 = __builtin_amdgcn_mfma_f32_32x32x16_bf16(vf[3], PB1, acc1, 0, 0, 0);
    __builtin_amdgcn_s_setprio(0);
  }

  // epilogue: O^T (d-major regs) -> LDS transpose -> coalesced row writes
  float rl = __builtin_amdgcn_rcpf(lsum);
#pragma unroll
  for (int dc = 0; dc < 2; ++dc) {
    f32x16 a = dc ? acc1 : acc0;
#pragma unroll
    for (int i = 0; i < 8; ++i) {
      uint32_t pkd = pkbf(a[2 * i] * rl, a[2 * i + 1] * rl);
      int d2 = (i & 1) + 4 * (i >> 1) + 2 * hi + dc * 16;
      els[w][lo][d2] = pkd;
    }
  }
  __syncthreads();
  unsigned short* yp = y + (size_t)b * Tx * Cx + h * Dx;
#pragma unroll
  for (int pp = 0; pp < 16; ++pp) {
    int qr = 2 * pp + hi;
    uint32_t val = els[w][qr][lo];
    *(uint32_t*)(yp + (size_t)(qbase + qr) * Cx + lo * 2) = val;
  }
}

}  // namespace

extern "C" void kernel_launch(void* const* d_in, const int* in_sizes, int n_in,
                              void* d_out, int out_size, void* d_ws, size_t ws_size,
                              hipStream_t stream) {
  const float* x = (const float*)d_in[0];
  const float* Wq = (const float*)d_in[1];
  const float* bq = (const float*)d_in[2];
  const float* Wk = (const float*)d_in[3];
  const float* bk = (const float*)d_in[4];
  const float* Wv = (const float*)d_in[5];
  const float* bv = (const float*)d_in[6];
  const float* Wp = (const float*)d_in[7];
  const float* bp = (const float*)d_in[8];

  unsigned short* xb = (unsigned short*)d_ws;                 // 8192*1024
  unsigned short* wt = xb + (size_t)Mx * Cx;                  // 4 * 1024*1024 (WqT,WkT,WvT,WpT)
  float* ct = (float*)(wt + (size_t)4 * Cx * Cx);             // 2048*32
  float* st = ct + Tx * 32;
  unsigned short* qb = (unsigned short*)(st + Tx * 32);       // q,k,v consecutive (split3 GEMM out)
  unsigned short* kb = qb + (size_t)Mx * Cx;
  unsigned short* vb = kb + (size_t)Mx * Cx;
  unsigned short* vT = vb + (size_t)Mx * Cx;
  unsigned short* yb = vT + (size_t)Mx * Cx;

  ca_cvt<<<dim3(2048), dim3(256), 0, stream>>>(x, xb, Mx * Cx / 4);
  ca_wt<<<dim3(32, 32), dim3(256), 0, stream>>>(Wq, wt + (size_t)0 * Cx * Cx);
  ca_wt<<<dim3(32, 32), dim3(256), 0, stream>>>(Wk, wt + (size_t)1 * Cx * Cx);
  ca_wt<<<dim3(32, 32), dim3(256), 0, stream>>>(Wv, wt + (size_t)2 * Cx * Cx);
  ca_wt<<<dim3(32, 32), dim3(256), 0, stream>>>(Wp, wt + (size_t)3 * Cx * Cx);
  ca_rtab<<<dim3(Tx * 32 / 256), dim3(256), 0, stream>>>(ct, st);

  ca_gemm<0><<<dim3(64, 24), dim3(256), 0, stream>>>(xb, wt, bq, bk, bv, qb, Mx, 3072, Cx);
  ca_rope<<<dim3(Mx * Cx / 8 / 256), dim3(256), 0, stream>>>(qb, kb, ct, st);
  ca_vt<<<dim3(Tx / 64, Bx * Hx), dim3(256), 0, stream>>>(vb, vT);
  ca_attn<<<dim3(64, 16), dim3(256), 0, stream>>>(qb, kb, vT, yb);
  ca_gemm<1><<<dim3(64, 8), dim3(256), 0, stream>>>(yb, wt + (size_t)3 * Cx * Cx, bp,
                                                    nullptr, nullptr, d_out, Mx, Cx, Cx);
}

// Round 6
// 266.287 us; speedup vs baseline: 2.4430x; 1.0317x over previous
//
#include <hip/hip_runtime.h>
#include <hip/hip_bf16.h>
#include <stdint.h>

namespace {

constexpr int Bx = 4, Tx = 2048, Cx = 1024, Hx = 16, Dx = 64;
constexpr int Mx = Bx * Tx;  // 8192

typedef __attribute__((ext_vector_type(8))) short bf16x8;
typedef __attribute__((ext_vector_type(4))) float f32x4;
typedef __attribute__((ext_vector_type(16))) float f32x16;
typedef __attribute__((ext_vector_type(2))) unsigned int u32x2;

__device__ __forceinline__ float b2f(unsigned short u) {
  unsigned int v = ((unsigned int)u) << 16;
  return __builtin_bit_cast(float, v);
}
__device__ __forceinline__ unsigned short f2b(float f) {
  unsigned int v = __builtin_bit_cast(unsigned int, f);
  v += 0x7fffu + ((v >> 16) & 1u);
  return (unsigned short)(v >> 16);
}
__device__ __forceinline__ uint32_t pkbf(float a, float b) {
  __hip_bfloat162 h = __float22bfloat162_rn(float2{a, b});
  uint32_t r;
  __builtin_memcpy(&r, &h, 4);  // __hip_bfloat162 not trivially copyable -> no bit_cast
  return r;
}
// permlane32_swap via builtin (compiler handles VALU->permlane hazards):
//   a_new[i] = i<32 ? a[i] : b[i-32];  b_new[i] = i<32 ? a[i+32] : b[i]
__device__ __forceinline__ void pl32swap(uint32_t& a, uint32_t& b) {
  u32x2 r = __builtin_amdgcn_permlane32_swap(a, b, false, false);
  a = r[0];
  b = r[1];
}
__device__ __forceinline__ float xhalf_max(float x) {
  uint32_t a = __builtin_bit_cast(uint32_t, x), b = a;
  pl32swap(a, b);
  return fmaxf(__builtin_bit_cast(float, a), __builtin_bit_cast(float, b));
}
__device__ __forceinline__ float xhalf_sum(float x) {
  uint32_t a = __builtin_bit_cast(uint32_t, x), b = a;
  pl32swap(a, b);
  return __builtin_bit_cast(float, a) + __builtin_bit_cast(float, b);
}

#define GLD16(g, lp) __builtin_amdgcn_global_load_lds(                     \
    (__attribute__((address_space(1))) void*)(g),                          \
    (__attribute__((address_space(3))) void*)(lp), 16, 0, 0)

// ---------------- convert fp32 -> bf16 (vectorized) ----------------
__global__ void ca_cvt(const float* __restrict__ src, unsigned short* __restrict__ dst, int n4) {
  int i = blockIdx.x * blockDim.x + threadIdx.x;
  int stride = gridDim.x * blockDim.x;
  for (; i < n4; i += stride) {
    float4 f = ((const float4*)src)[i];
    ushort4 o;
    o.x = f2b(f.x); o.y = f2b(f.y); o.z = f2b(f.z); o.w = f2b(f.w);
    ((ushort4*)dst)[i] = o;
  }
}

// ---------------- W (K x N) -> Wt (N x K) bf16 ----------------
__global__ void ca_wt(const float* __restrict__ W, unsigned short* __restrict__ Wt) {
  __shared__ float tile[32][33];
  int n0 = blockIdx.x * 32, k0 = blockIdx.y * 32;
  int j = threadIdx.x & 31, i = threadIdx.x >> 5;  // i in 0..7
#pragma unroll
  for (int r = 0; r < 4; ++r)
    tile[i + 8 * r][j] = W[(size_t)(k0 + i + 8 * r) * Cx + n0 + j];
  __syncthreads();
#pragma unroll
  for (int r = 0; r < 4; ++r)
    Wt[(size_t)(n0 + i + 8 * r) * Cx + k0 + j] = f2b(tile[j][i + 8 * r]);
}

// ---------------- RoPE cos/sin table ----------------
__global__ void ca_rtab(float* __restrict__ ct, float* __restrict__ st) {
  int idx = blockIdx.x * blockDim.x + threadIdx.x;  // < Tx*32
  int t = idx >> 5, i = idx & 31;
  float fr = expf((float)i * -0.29710775393471563f);  // -ln(10000)/31
  float a = (float)t * fr;
  ct[idx] = cosf(a);
  st[idx] = sinf(a);
}

// ---------------- GEMM: A (MxK bf16) x Bt (NxK bf16) + bias ----------------
// m97 structure: 128x128 tile, BK=32, global_load_lds width-16, 2-barrier loop.
template <int MODE>
__global__ __launch_bounds__(256) void ca_gemm(
    const unsigned short* __restrict__ A, const unsigned short* __restrict__ Bt,
    const float* __restrict__ b0, const float* __restrict__ b1, const float* __restrict__ b2,
    void* __restrict__ out, int M, int N, int K) {
  __shared__ __align__(16) unsigned short Al[128 * 32];
  __shared__ __align__(16) unsigned short Bl[128 * 32];
  int tid = threadIdx.x;
  int w = tid >> 6, l = tid & 63;
  int m0 = blockIdx.x * 128, n0 = blockIdx.y * 128;
  int wm = (w >> 1) * 64, wn = (w & 1) * 64;
  f32x4 acc[4][4] = {};

  int lr = l & 15, lk8 = (l >> 4) * 8;
  int srow = w * 32 + (l >> 2), scol = (l & 3) * 8;
  const unsigned short* ga0 = A + (size_t)(m0 + srow) * K + scol;
  const unsigned short* gb0 = Bt + (size_t)(n0 + srow) * K + scol;
  unsigned short* la = &Al[w * 1024];
  unsigned short* lb = &Bl[w * 1024];
  int nk = K / 32;
  for (int kt = 0; kt < nk; ++kt) {
    const unsigned short* ga = ga0 + kt * 32;
    const unsigned short* gb = gb0 + kt * 32;
    GLD16(ga, la);
    GLD16(ga + (size_t)16 * K, la + 512);
    GLD16(gb, lb);
    GLD16(gb + (size_t)16 * K, lb + 512);
    __syncthreads();
    bf16x8 af[4], bfr[4];
#pragma unroll
    for (int mi = 0; mi < 4; ++mi) af[mi] = *(const bf16x8*)&Al[(wm + mi * 16 + lr) * 32 + lk8];
#pragma unroll
    for (int ni = 0; ni < 4; ++ni) bfr[ni] = *(const bf16x8*)&Bl[(wn + ni * 16 + lr) * 32 + lk8];
#pragma unroll
    for (int mi = 0; mi < 4; ++mi)
#pragma unroll
      for (int ni = 0; ni < 4; ++ni)
        acc[mi][ni] = __builtin_amdgcn_mfma_f32_16x16x32_bf16(af[mi], bfr[ni], acc[mi][ni], 0, 0, 0);
    __syncthreads();
  }

  int lq4 = (l >> 4) * 4;
  if (MODE == 0) {
    int which = n0 >> 10;
    int nb = n0 & 1023;
    const float* bias = which == 0 ? b0 : (which == 1 ? b1 : b2);
    unsigned short* o = (unsigned short*)out + (size_t)which * M * 1024;
#pragma unroll
    for (int mi = 0; mi < 4; ++mi)
#pragma unroll
      for (int ni = 0; ni < 4; ++ni) {
        int ncol = nb + wn + ni * 16 + lr;
        float bv = bias[ncol];
#pragma unroll
        for (int rg = 0; rg < 4; ++rg) {
          int m = m0 + wm + mi * 16 + lq4 + rg;
          o[(size_t)m * 1024 + ncol] = f2b(acc[mi][ni][rg] + bv);
        }
      }
  } else {
    float* o = (float*)out;
#pragma unroll
    for (int mi = 0; mi < 4; ++mi)
#pragma unroll
      for (int ni = 0; ni < 4; ++ni) {
        int ncol = n0 + wn + ni * 16 + lr;
        float bv = b0[ncol];
#pragma unroll
        for (int rg = 0; rg < 4; ++rg) {
          int m = m0 + wm + mi * 16 + lq4 + rg;
          o[(size_t)m * N + ncol] = acc[mi][ni][rg] + bv;
        }
      }
  }
}

// ---------------- RoPE apply (in-place on q and k, bf16) ----------------
// Q is additionally pre-scaled by 0.125*log2(e) so attention scores come out
// of the QK^T MFMA directly in log2 domain.
__global__ void ca_rope(unsigned short* __restrict__ q, unsigned short* __restrict__ k,
                        const float* __restrict__ ct, const float* __restrict__ st) {
  constexpr float SC = 0.18033688011112042f;  // 0.125 * log2(e)
  int p = blockIdx.x * blockDim.x + threadIdx.x;  // handles 8 elems (4 pairs)
  int e = p * 8;
  int col = e & (Cx - 1);
  int t = (e >> 10) & (Tx - 1);
  int j0 = (col & (Dx - 1)) >> 1;
  float c[4], s[4];
#pragma unroll
  for (int jj = 0; jj < 4; ++jj) {
    c[jj] = ct[t * 32 + j0 + jj];
    s[jj] = st[t * 32 + j0 + jj];
  }
  {
    uint4 v = *(uint4*)&q[e];
    unsigned short* u = (unsigned short*)&v;
#pragma unroll
    for (int pr = 0; pr < 4; ++pr) {
      float xr = b2f(u[2 * pr]), xi = b2f(u[2 * pr + 1]);
      u[2 * pr] = f2b((xr * c[pr] - xi * s[pr]) * SC);
      u[2 * pr + 1] = f2b((xr * s[pr] + xi * c[pr]) * SC);
    }
    *(uint4*)&q[e] = v;
  }
  {
    uint4 v = *(uint4*)&k[e];
    unsigned short* u = (unsigned short*)&v;
#pragma unroll
    for (int pr = 0; pr < 4; ++pr) {
      float xr = b2f(u[2 * pr]), xi = b2f(u[2 * pr + 1]);
      u[2 * pr] = f2b(xr * c[pr] - xi * s[pr]);
      u[2 * pr + 1] = f2b(xr * s[pr] + xi * c[pr]);
    }
    *(uint4*)&k[e] = v;
  }
}

// ---------------- V (B,T,C) -> vT (B,H,D,T) ----------------
__global__ void ca_vt(const unsigned short* __restrict__ v, unsigned short* __restrict__ vT) {
  __shared__ __align__(16) unsigned short tl[64][72];
  int t0 = blockIdx.x * 64;
  int bh = blockIdx.y;
  int b = bh >> 4, h = bh & 15;
  int tid = threadIdx.x;
  const unsigned short* vb = v + (size_t)b * Tx * Cx + h * Dx;
#pragma unroll
  for (int it = 0; it < 2; ++it) {
    int tt = it * 32 + (tid >> 3), d0 = (tid & 7) * 8;
    uint4 x = *(const uint4*)&vb[(size_t)(t0 + tt) * Cx + d0];
    unsigned short* u = (unsigned short*)&x;
#pragma unroll
    for (int jj = 0; jj < 8; ++jj) tl[d0 + jj][tt] = u[jj];
  }
  __syncthreads();
  unsigned short* o = vT + (size_t)bh * Dx * Tx;
#pragma unroll
  for (int it = 0; it < 2; ++it) {
    int d = it * 32 + (tid >> 3), tc = (tid & 7) * 8;
    *(uint4*)&o[(size_t)d * Tx + t0 + tc] = *(const uint4*)&tl[d][tc];
  }
}

// ---------------- causal flash attention -------------------------------------
// 1-wave (64-thread) blocks: grid (bh=64, 64 q-tiles of 32 rows). 4096
// independent waves -> ~16 blocks/CU resident (vs 4 with the old 4-wave
// blocks): the serial per-tile chain (QK mfma -> softmax -> pack -> PV mfma)
// is latency-bound, so occupancy is the lever (r5 post-mortem: VALU diet was
// neutral at identical dur; both pipes <50% busy, occupancy 20%).
__global__ __launch_bounds__(64) void ca_attn(
    const unsigned short* __restrict__ q, const unsigned short* __restrict__ k,
    const unsigned short* __restrict__ vT, unsigned short* __restrict__ y) {
  __shared__ uint32_t els[32][33];
  int l = threadIdx.x & 63;
  int bh = blockIdx.x;                              // XCD = id%8 = bh%8 -> KV L2-pinned
  int qt = (int)gridDim.y - 1 - (int)blockIdx.y;    // heavy q-tiles first
  int b = bh >> 4, h = bh & 15;
  const unsigned short* qp = q + (size_t)b * Tx * Cx + h * Dx;
  const unsigned short* kp = k + (size_t)b * Tx * Cx + h * Dx;
  const unsigned short* vp = vT + (size_t)bh * Dx * Tx;
  int qbase = qt * 32;
  int lo = l & 31, hi = l >> 5;

  bf16x8 qf[4];
  {
    const unsigned short* qr = qp + (size_t)(qbase + lo) * Cx + hi * 8;
#pragma unroll
    for (int c = 0; c < 4; ++c) qf[c] = *(const bf16x8*)(qr + c * 16);
  }

  f32x16 acc0 = {}, acc1 = {};
  float m = -__builtin_inff(), lsum = 0.f;
  int nt = qt + 1;

  uint4 rk[4], rv[4];
  const unsigned short* kr0 = kp + (size_t)lo * Cx + hi * 8;
  const unsigned short* vr0 = vp + (size_t)lo * Tx + hi * 8;
  auto loadK = [&](int t) {
    const unsigned short* kr = kr0 + (size_t)t * 32 * Cx;
#pragma unroll
    for (int c = 0; c < 4; ++c) rk[c] = *(const uint4*)(kr + c * 16);
  };
  auto loadV = [&](int t) {
#pragma unroll
    for (int dc = 0; dc < 2; ++dc)
#pragma unroll
      for (int kc = 0; kc < 2; ++kc)
        rv[dc * 2 + kc] = *(const uint4*)(vr0 + (size_t)dc * 32 * Tx + t * 32 + kc * 16);
  };
  loadK(0);
  loadV(0);

  for (int t = 0; t < nt; ++t) {
    bf16x8 kf[4], vf[4];
#pragma unroll
    for (int c = 0; c < 4; ++c) kf[c] = __builtin_bit_cast(bf16x8, rk[c]);
#pragma unroll
    for (int c = 0; c < 4; ++c) vf[c] = __builtin_bit_cast(bf16x8, rv[c]);
    if (t + 1 < nt) { loadK(t + 1); loadV(t + 1); }  // prefetch under softmax

    __builtin_amdgcn_s_setprio(1);
    f32x16 s = {};
#pragma unroll
    for (int c = 0; c < 4; ++c)
      s = __builtin_amdgcn_mfma_f32_32x32x16_bf16(kf[c], qf[c], s, 0, 0, 0);
    __builtin_amdgcn_s_setprio(0);

    // scores already in log2 domain (Q pre-scaled by 0.125*log2e in ca_rope)
    float tv[16];
#pragma unroll
    for (int r = 0; r < 16; ++r) tv[r] = s[r];
    if (t == nt - 1) {  // diagonal tile is exactly the last tile
#pragma unroll
      for (int r = 0; r < 16; ++r) {
        int kvr = (r & 3) + 8 * (r >> 2) + 4 * hi;
        if (kvr > lo) tv[r] = -3.0e38f;
      }
    }
    // balanced max tree (fuses to v_max3)
    float mx[8];
#pragma unroll
    for (int r = 0; r < 8; ++r) mx[r] = fmaxf(tv[2 * r], tv[2 * r + 1]);
#pragma unroll
    for (int r = 0; r < 4; ++r) mx[r] = fmaxf(mx[2 * r], mx[2 * r + 1]);
    float pmax = fmaxf(fmaxf(mx[0], mx[1]), fmaxf(mx[2], mx[3]));
    pmax = xhalf_max(pmax);
    if (!__all(pmax - m <= 11.0f)) {  // defer-max (T13), log2 units
      float mn = fmaxf(m, pmax);
      float al = exp2f(m - mn);
      m = mn;
      lsum *= al;
#pragma unroll
      for (int r = 0; r < 16; ++r) { acc0[r] *= al; acc1[r] *= al; }
    }
    float p[16];
#pragma unroll
    for (int r = 0; r < 16; ++r) p[r] = exp2f(tv[r] - m);
    // balanced sum tree
    float sm[8];
#pragma unroll
    for (int r = 0; r < 8; ++r) sm[r] = p[2 * r] + p[2 * r + 1];
#pragma unroll
    for (int r = 0; r < 4; ++r) sm[r] = sm[2 * r] + sm[2 * r + 1];
    float ps = (sm[0] + sm[1]) + (sm[2] + sm[3]);
    lsum += xhalf_sum(ps);

    // pack P -> bf16 pairs; kv redistribution via 4 permlane32_swap
    uint32_t pk[8];
#pragma unroll
    for (int i = 0; i < 8; ++i) pk[i] = pkbf(p[2 * i], p[2 * i + 1]);
    pl32swap(pk[0], pk[2]);
    pl32swap(pk[1], pk[3]);
    pl32swap(pk[4], pk[6]);
    pl32swap(pk[5], pk[7]);
    uint4 xw{pk[0], pk[1], pk[2], pk[3]}, yw{pk[4], pk[5], pk[6], pk[7]};
    bf16x8 PB0 = __builtin_bit_cast(bf16x8, xw);
    bf16x8 PB1 = __builtin_bit_cast(bf16x8, yw);
    __builtin_amdgcn_s_setprio(1);
    acc0 = __builtin_amdgcn_mfma_f32_32x32x16_bf16(vf[0], PB0, acc0, 0, 0, 0);
    acc0 = __builtin_amdgcn_mfma_f32_32x32x16_bf16(vf[1], PB1, acc0, 0, 0, 0);
    acc1 = __builtin_amdgcn_mfma_f32_32x32x16_bf16(vf[2], PB0, acc1, 0, 0, 0);
    acc1 = __builtin_amdgcn_mfma_f32_32x32x16_bf16(vf[3], PB1, acc1, 0, 0, 0);
    __builtin_amdgcn_s_setprio(0);
  }

  // epilogue: O^T (d-major regs) -> LDS transpose -> coalesced row writes
  float rl = __builtin_amdgcn_rcpf(lsum);
#pragma unroll
  for (int dc = 0; dc < 2; ++dc) {
    f32x16 a = dc ? acc1 : acc0;
#pragma unroll
    for (int i = 0; i < 8; ++i) {
      uint32_t pkd = pkbf(a[2 * i] * rl, a[2 * i + 1] * rl);
      int d2 = (i & 1) + 4 * (i >> 1) + 2 * hi + dc * 16;
      els[lo][d2] = pkd;
    }
  }
  __syncthreads();
  unsigned short* yp = y + (size_t)b * Tx * Cx + h * Dx;
#pragma unroll
  for (int pp = 0; pp < 16; ++pp) {
    int qr = 2 * pp + hi;
    uint32_t val = els[qr][lo];
    *(uint32_t*)(yp + (size_t)(qbase + qr) * Cx + lo * 2) = val;
  }
}

}  // namespace

extern "C" void kernel_launch(void* const* d_in, const int* in_sizes, int n_in,
                              void* d_out, int out_size, void* d_ws, size_t ws_size,
                              hipStream_t stream) {
  const float* x = (const float*)d_in[0];
  const float* Wq = (const float*)d_in[1];
  const float* bq = (const float*)d_in[2];
  const float* Wk = (const float*)d_in[3];
  const float* bk = (const float*)d_in[4];
  const float* Wv = (const float*)d_in[5];
  const float* bv = (const float*)d_in[6];
  const float* Wp = (const float*)d_in[7];
  const float* bp = (const float*)d_in[8];

  unsigned short* xb = (unsigned short*)d_ws;                 // 8192*1024
  unsigned short* wt = xb + (size_t)Mx * Cx;                  // 4 * 1024*1024 (WqT,WkT,WvT,WpT)
  float* ct = (float*)(wt + (size_t)4 * Cx * Cx);             // 2048*32
  float* st = ct + Tx * 32;
  unsigned short* qb = (unsigned short*)(st + Tx * 32);       // q,k,v consecutive (split3 GEMM out)
  unsigned short* kb = qb + (size_t)Mx * Cx;
  unsigned short* vb = kb + (size_t)Mx * Cx;
  unsigned short* vT = vb + (size_t)Mx * Cx;
  unsigned short* yb = vT + (size_t)Mx * Cx;

  ca_cvt<<<dim3(2048), dim3(256), 0, stream>>>(x, xb, Mx * Cx / 4);
  ca_wt<<<dim3(32, 32), dim3(256), 0, stream>>>(Wq, wt + (size_t)0 * Cx * Cx);
  ca_wt<<<dim3(32, 32), dim3(256), 0, stream>>>(Wk, wt + (size_t)1 * Cx * Cx);
  ca_wt<<<dim3(32, 32), dim3(256), 0, stream>>>(Wv, wt + (size_t)2 * Cx * Cx);
  ca_wt<<<dim3(32, 32), dim3(256), 0, stream>>>(Wp, wt + (size_t)3 * Cx * Cx);
  ca_rtab<<<dim3(Tx * 32 / 256), dim3(256), 0, stream>>>(ct, st);

  ca_gemm<0><<<dim3(64, 24), dim3(256), 0, stream>>>(xb, wt, bq, bk, bv, qb, Mx, 3072, Cx);
  ca_rope<<<dim3(Mx * Cx / 8 / 256), dim3(256), 0, stream>>>(qb, kb, ct, st);
  ca_vt<<<dim3(Tx / 64, Bx * Hx), dim3(256), 0, stream>>>(vb, vT);
  ca_attn<<<dim3(64, 64), dim3(64), 0, stream>>>(qb, kb, vT, yb);
  ca_gemm<1><<<dim3(64, 8), dim3(256), 0, stream>>>(yb, wt + (size_t)3 * Cx * Cx, bp,
                                                    nullptr, nullptr, d_out, Mx, Cx, Cx);
}